// Round 1
// baseline (4481.043 us; speedup 1.0000x reference)
//
#include <hip/hip_runtime.h>
#include <stdint.h>

typedef unsigned long long u64;

#define NVAR 8192
#define NCLS 32768
#define CSEG 16

__device__ __forceinline__ float lane_bc(float v, int l) { return __shfl(v, l); }
__device__ __forceinline__ u64 shfl_u64(u64 v, int l) {
  unsigned lo = __shfl((unsigned)v, l);
  unsigned hi = __shfl((unsigned)(v >> 32), l);
  return ((u64)hi << 32) | (u64)lo;
}

// ---------------- kernel 1: vars_fwd = v @ fb0^T  [NVAR,64] ----------------
__global__ __launch_bounds__(256) void k_varsfwd(const float* __restrict__ v,
                                                 const float* __restrict__ fb0,
                                                 float* __restrict__ out) {
  __shared__ float fbt[64 * 64];   // fbt[k][d] = fb0[d][k]
  __shared__ float vrow[4][64];
  int t = threadIdx.x;
#pragma unroll
  for (int i = 0; i < 16; ++i) {
    int idx = i * 256 + t;                       // idx = d*64+k
    fbt[(idx & 63) * 64 + (idx >> 6)] = fb0[idx];
  }
  __syncthreads();
  int w = t >> 6, lane = t & 63;
  for (int rr = 0; rr < 16; rr += 4) {
    int row = blockIdx.x * 16 + rr + w;
    vrow[w][lane] = v[row * 64 + lane];
    __syncthreads();
    double a = 0.0;
#pragma unroll
    for (int k = 0; k < 64; ++k)
      a = fma((double)vrow[w][k], (double)fbt[k * 64 + lane], a);
    out[row * 64 + lane] = (float)a;
    __syncthreads();
  }
}

// ------- pass 1: c = relu(cm@vars_fwd + cb); dmat = c @ fb1^T; emit bitmasks -------
template <bool WB>
__global__ __launch_bounds__(256) void k_pass1(
    const float* __restrict__ pos, const float* __restrict__ neg,
    const float* __restrict__ bmat, const float* __restrict__ fb1,
    const float* __restrict__ cbias, float* __restrict__ dmat,
    u64* __restrict__ mbits, u64* __restrict__ sbits) {
  __shared__ float fbt[64 * 64];   // fbt[k][d] = fb1[d][k]
  __shared__ float crow[4][64];
  int t = threadIdx.x;
#pragma unroll
  for (int i = 0; i < 16; ++i) {
    int idx = i * 256 + t;
    fbt[(idx & 63) * 64 + (idx >> 6)] = fb1[idx];
  }
  __syncthreads();
  int w = t >> 6, lane = t & 63;
  int c = blockIdx.x * 4 + w;
  const float4* prow = (const float4*)(pos + (size_t)c * NVAR);
  const float4* nrow = (const float4*)(neg + (size_t)c * NVAR);
  int cbi = c >> 6, cl = c & 63;
  double acc = 0.0;   // exact: sums of (+-1)*f32 products
  for (int g = 0; g < 32; ++g) {
    float4 p = prow[g * 64 + lane];
    float4 q = nrow[g * 64 + lane];
    float sc[4];
    sc[0] = p.x - q.x; sc[1] = p.y - q.y; sc[2] = p.z - q.z; sc[3] = p.w - q.w;
#pragma unroll
    for (int j = 0; j < 4; ++j) {
      float s = sc[j];
      u64 m = __ballot(s != 0.f);
      if (WB) {
        u64 sg = __ballot(s < 0.f);
        if (lane == 0) {
          size_t widx = ((size_t)((g << 2) + j) * 512 + cbi) * 64 + cl;
          mbits[widx] = m;
          sbits[widx] = sg;
        }
      }
      while (m) {
        int l = __builtin_ctzll(m);
        m &= m - 1;
        float sval = lane_bc(s, l);   // exactly +-1
        const float* brow = bmat + (size_t)((g << 8) + (l << 2) + j) * 64;
        acc += (double)(sval * brow[lane]);   // product exact in f32
      }
    }
  }
  float cv = fmaxf((float)acc + cbias[lane], 0.f);
  crow[w][lane] = cv;
  __syncthreads();
  double da = 0.0;
#pragma unroll
  for (int k = 0; k < 64; ++k)
    da = fma((double)crow[w][k], (double)fbt[k * 64 + lane], da);
  dmat[(size_t)c * 64 + lane] = (float)da;
}

// ------- pass 2 (fast): nv = cm^T @ dmat using packed bitmasks -------
__global__ __launch_bounds__(256) void k_pass2_bits(
    const u64* __restrict__ mbits, const u64* __restrict__ sbits,
    const float* __restrict__ dmat, float* __restrict__ nv) {
  __shared__ float acc[256 * 64];   // [vloc][d], 64 KiB
  int t = threadIdx.x;
#pragma unroll
  for (int i = 0; i < 64; ++i) acc[i * 256 + t] = 0.f;
  __syncthreads();
  int w = t >> 6, lane = t & 63;
  int g = blockIdx.x / CSEG, seg = blockIdx.x % CSEG;
  int cb0 = seg * (512 / CSEG);
  for (int b = cb0 + w; b < cb0 + 512 / CSEG; b += 4) {
    u64 m[4], sg[4];
#pragma unroll
    for (int j = 0; j < 4; ++j) {
      size_t base = ((size_t)((g << 2) + j) * 512 + b) * 64 + lane;
      m[j] = mbits[base];
      sg[j] = sbits[base];
    }
    for (int jj = 0; jj < 64; ++jj) {
      u64 mj[4];
#pragma unroll
      for (int j = 0; j < 4; ++j) mj[j] = shfl_u64(m[j], jj);
      if (!(mj[0] | mj[1] | mj[2] | mj[3])) continue;
      float dv = dmat[(size_t)((b << 6) + jj) * 64 + lane];
#pragma unroll
      for (int j = 0; j < 4; ++j) {
        u64 mm = mj[j];
        if (!mm) continue;
        u64 sj = shfl_u64(sg[j], jj);
        while (mm) {
          int l = __builtin_ctzll(mm);
          mm &= mm - 1;
          float val = ((sj >> l) & 1) ? -dv : dv;
          atomicAdd(&acc[((l << 2) + j) * 64 + lane], val);
        }
      }
    }
  }
  __syncthreads();
  size_t obase = (size_t)g * 16384;
#pragma unroll
  for (int i = 0; i < 64; ++i) {
    int idx = i * 256 + t;
    atomicAdd(&nv[obase + idx], acc[idx]);
  }
}

// ------- pass 2 (fallback): re-read pos/neg directly -------
__global__ __launch_bounds__(256) void k_pass2_dense(
    const float* __restrict__ pos, const float* __restrict__ neg,
    const float* __restrict__ dmat, float* __restrict__ nv) {
  __shared__ float acc[64 * 64];
  int t = threadIdx.x;
#pragma unroll
  for (int i = 0; i < 16; ++i) acc[i * 256 + t] = 0.f;
  __syncthreads();
  int w = t >> 6, lane = t & 63;
  int s = blockIdx.x / CSEG, seg = blockIdx.x % CSEG;
  int c0 = seg * (NCLS / CSEG);
  for (int c = c0 + w; c < c0 + NCLS / CSEG; c += 4) {
    float p = pos[(size_t)c * NVAR + (s << 6) + lane];
    float q = neg[(size_t)c * NVAR + (s << 6) + lane];
    float sv = p - q;
    u64 m = __ballot(sv != 0.f);
    if (!m) continue;
    float dv = dmat[(size_t)c * 64 + lane];
    while (m) {
      int l = __builtin_ctzll(m);
      m &= m - 1;
      float sl = lane_bc(sv, l);
      atomicAdd(&acc[(l << 6) + lane], sl * dv);
    }
  }
  __syncthreads();
  size_t obase = (size_t)s * 4096;
#pragma unroll
  for (int i = 0; i < 16; ++i) {
    int idx = i * 256 + t;
    atomicAdd(&nv[obase + idx], acc[idx]);
  }
}

// ------- tail 1: ve2 = tanh(cat(ground, relu(nv+vb)) @ Wg^T + bg) -------
__global__ __launch_bounds__(256) void k_tail1(
    const float* __restrict__ nv, const float* __restrict__ vb,
    const float* __restrict__ ground, const float* __restrict__ Wg,
    const float* __restrict__ bg, float* __restrict__ ve2out) {
  __shared__ float wt[72 * 64];   // wt[k][d] = Wg[d][k]
  __shared__ float inrow[4][72];
  int t = threadIdx.x;
#pragma unroll
  for (int i = 0; i < 18; ++i) {
    int idx = i * 256 + t;                       // d*72+k
    wt[(idx % 72) * 64 + (idx / 72)] = Wg[idx];
  }
  __syncthreads();
  int w = t >> 6, lane = t & 63;
  for (int rr = 0; rr < 32; rr += 4) {
    int row = blockIdx.x * 32 + rr + w;
    float ve = fmaxf(nv[row * 64 + lane] + vb[lane], 0.f);
    inrow[w][8 + lane] = ve;
    if (lane < 8) inrow[w][lane] = ground[row * 8 + lane];
    __syncthreads();
    double a = 0.0;
#pragma unroll
    for (int k = 0; k < 72; ++k)
      a = fma((double)inrow[w][k], (double)wt[k * 64 + lane], a);
    ve2out[row * 64 + lane] = tanhf((float)a + bg[lane]);
    __syncthreads();
  }
}

// ------- tail GRU: M=0 -> z, M=1 -> rp=r*prev, M=2 -> h & final output -------
template <int M>
__global__ __launch_bounds__(256) void k_tailg(
    const float* __restrict__ ve2, const float* __restrict__ in2,
    const float* __restrict__ W, const float* __restrict__ U,
    const float* __restrict__ bias, const float* __restrict__ prev,
    const float* __restrict__ zbuf, float* __restrict__ outbuf) {
  __shared__ float wt[64 * 64], ut[64 * 64];
  __shared__ float xr[4][64], yr[4][64];
  int t = threadIdx.x;
#pragma unroll
  for (int i = 0; i < 16; ++i) {
    int idx = i * 256 + t;
    wt[(idx & 63) * 64 + (idx >> 6)] = W[idx];
    ut[(idx & 63) * 64 + (idx >> 6)] = U[idx];
  }
  __syncthreads();
  int w = t >> 6, lane = t & 63;
  for (int rr = 0; rr < 32; rr += 4) {
    int row = blockIdx.x * 32 + rr + w;
    xr[w][lane] = ve2[row * 64 + lane];
    yr[w][lane] = in2[row * 64 + lane];
    __syncthreads();
    float a = bias[lane];
#pragma unroll
    for (int k = 0; k < 64; ++k) a = fmaf(xr[w][k], wt[k * 64 + lane], a);
#pragma unroll
    for (int k = 0; k < 64; ++k) a = fmaf(yr[w][k], ut[k * 64 + lane], a);
    float res;
    if (M == 0) {
      res = 1.f / (1.f + expf(-a));
    } else if (M == 1) {
      float r = 1.f / (1.f + expf(-a));
      res = r * prev[row * 64 + lane];
    } else {
      float h = tanhf(a);
      float z = zbuf[row * 64 + lane];
      float p = prev[row * 64 + lane];
      res = (1.f - z) * p + z * h;
    }
    outbuf[row * 64 + lane] = res;
    __syncthreads();
  }
}

extern "C" void kernel_launch(void* const* d_in, const int* in_sizes, int n_in,
                              void* d_out, int out_size, void* d_ws, size_t ws_size,
                              hipStream_t stream) {
  const float* variables = (const float*)d_in[0];
  const float* ground    = (const float*)d_in[1];
  const float* cpos      = (const float*)d_in[2];
  const float* cneg      = (const float*)d_in[3];
  const float* fb        = (const float*)d_in[6];
  const float* vb        = (const float*)d_in[7];
  const float* cb        = (const float*)d_in[8];
  const float* Wg        = (const float*)d_in[9];
  const float* bg        = (const float*)d_in[10];
  const float* Wz        = (const float*)d_in[11];
  const float* Uz        = (const float*)d_in[12];
  const float* bz        = (const float*)d_in[13];
  const float* Wr        = (const float*)d_in[14];
  const float* Ur        = (const float*)d_in[15];
  const float* br        = (const float*)d_in[16];
  const float* Wh        = (const float*)d_in[17];
  const float* Uh        = (const float*)d_in[18];
  const float* bh        = (const float*)d_in[19];
  float* out = (float*)d_out;
  char* ws = (char*)d_ws;
  const size_t MB = (size_t)1 << 20;

  float* vfwd  = (float*)(ws + 0);        // 2 MB (later reused as ve2)
  float* dmat  = (float*)(ws + 2 * MB);   // 8 MB
  float* nv    = (float*)(ws + 10 * MB);  // 2 MB
  float* zbuf  = (float*)(ws + 12 * MB);  // 2 MB
  float* rpbuf = (float*)(ws + 14 * MB);  // 2 MB
  u64* mbits   = (u64*)(ws + 16 * MB);    // 32 MB
  u64* sbits   = (u64*)(ws + 48 * MB);    // 32 MB
  bool fast = ws_size >= 80 * MB;

  k_varsfwd<<<512, 256, 0, stream>>>(variables, fb, vfwd);
  if (fast)
    k_pass1<true><<<8192, 256, 0, stream>>>(cpos, cneg, vfwd, fb + 4096, cb,
                                            dmat, mbits, sbits);
  else
    k_pass1<false><<<8192, 256, 0, stream>>>(cpos, cneg, vfwd, fb + 4096, cb,
                                             dmat, mbits, sbits);
  hipMemsetAsync(nv, 0, (size_t)NVAR * 64 * sizeof(float), stream);
  if (fast)
    k_pass2_bits<<<32 * CSEG, 256, 0, stream>>>(mbits, sbits, dmat, nv);
  else
    k_pass2_dense<<<128 * CSEG, 256, 0, stream>>>(cpos, cneg, dmat, nv);
  k_tail1<<<256, 256, 0, stream>>>(nv, vb, ground, Wg, bg, vfwd);
  k_tailg<0><<<256, 256, 0, stream>>>(vfwd, variables, Wz, Uz, bz, variables,
                                      nullptr, zbuf);
  k_tailg<1><<<256, 256, 0, stream>>>(vfwd, variables, Wr, Ur, br, variables,
                                      nullptr, rpbuf);
  k_tailg<2><<<256, 256, 0, stream>>>(vfwd, rpbuf, Wh, Uh, bh, variables, zbuf,
                                      out);
}

// Round 2
// 1884.123 us; speedup vs baseline: 2.3783x; 2.3783x over previous
//
#include <hip/hip_runtime.h>
#include <stdint.h>

typedef unsigned long long u64;

#define NVAR 8192
#define NCLS 32768
#define CSEG 16

__device__ __forceinline__ float lane_bc(float v, int l) { return __shfl(v, l); }

// ---------------- kernel 1: vars_fwd = v @ fb0^T  [NVAR,64] ----------------
__global__ __launch_bounds__(256) void k_varsfwd(const float* __restrict__ v,
                                                 const float* __restrict__ fb0,
                                                 float* __restrict__ out) {
  __shared__ float fbt[64 * 64];   // fbt[k][d] = fb0[d][k]
  __shared__ float vrow[4][64];
  int t = threadIdx.x;
#pragma unroll
  for (int i = 0; i < 16; ++i) {
    int idx = i * 256 + t;                       // idx = d*64+k
    fbt[(idx & 63) * 64 + (idx >> 6)] = fb0[idx];
  }
  __syncthreads();
  int w = t >> 6, lane = t & 63;
  for (int rr = 0; rr < 16; rr += 4) {
    int row = blockIdx.x * 16 + rr + w;
    vrow[w][lane] = v[row * 64 + lane];
    __syncthreads();
    double a = 0.0;
#pragma unroll
    for (int k = 0; k < 64; ++k)
      a = fma((double)vrow[w][k], (double)fbt[k * 64 + lane], a);
    out[row * 64 + lane] = (float)a;
    __syncthreads();
  }
}

// ======================= FAST PATH =======================
// pass 1 (fused): per block = 64 clauses (one clause-chunk cbi).
//   c = relu(cm @ vars_fwd + cb); dmat = c @ fb1^T
//   AND emit TRANSPOSED bitmasks vbs[var][cchunk][2] = {presence, sign}
//   (bit cl of word = clause cbi*64+cl).
__global__ __launch_bounds__(512, 4) void k_pass1t(
    const float* __restrict__ pos, const float* __restrict__ neg,
    const float* __restrict__ vfwd, const float* __restrict__ fb1,
    const float* __restrict__ cbias, float* __restrict__ dmat,
    u64* __restrict__ vbs) {
  __shared__ float fbt[64 * 64];   // fbt[k][d] = fb1[d][k]
  __shared__ u64 lm[64][4];        // [clause_local][j] presence over 64 vars
  __shared__ u64 lsg[64][4];       // sign bits
  __shared__ float crow[8][64];
  int t = threadIdx.x;
#pragma unroll
  for (int i = 0; i < 8; ++i) {
    int idx = i * 512 + t;
    fbt[(idx & 63) * 64 + (idx >> 6)] = fb1[idx];
  }
  int w = __builtin_amdgcn_readfirstlane(t >> 6);   // warp id 0..7 (SGPR)
  int lane = t & 63;
  int cbi = blockIdx.x;            // clause chunk 0..511
  int c0 = cbi * 64;
  double acc[8];
#pragma unroll
  for (int i = 0; i < 8; ++i) acc[i] = 0.0;
  __syncthreads();

  for (int g = 0; g < 32; ++g) {   // 32 groups of 256 variables
    for (int i = 0; i < 8; ++i) {
      int cl = w * 8 + i;          // local clause
      size_t rb = (size_t)(c0 + cl) * 2048 + (size_t)g * 64 + lane; // float4 units
      float4 p = ((const float4*)pos)[rb];
      float4 q = ((const float4*)neg)[rb];
      float sc[4];
      sc[0] = p.x - q.x; sc[1] = p.y - q.y; sc[2] = p.z - q.z; sc[3] = p.w - q.w;
#pragma unroll
      for (int j = 0; j < 4; ++j) {
        float s = sc[j];
        u64 m = __ballot(s != 0.f);
        u64 sg = __ballot(s < 0.f);
        if (lane == j) { lm[cl][j] = m; lsg[cl][j] = sg; }
        while (m) {                // ~10 set bits per (clause, g)
          int l = __builtin_ctzll(m);
          m &= m - 1;
          float dv = vfwd[(size_t)((g << 8) + (l << 2) + j) * 64 + lane];
          acc[i] += ((sg >> l) & 1) ? -(double)dv : (double)dv;  // exact products
        }
      }
    }
    __syncthreads();
    // bit-transpose the 64x64 tiles: warps 0-3 -> presence of tile j=w,
    // warps 4-7 -> sign of tile j=w-4. Output word over clauses per var.
    {
      int j = w & 3;
      u64 row = (w < 4) ? lm[lane][j] : lsg[lane][j];   // lane = clause
      u64 keep = 0;
#pragma unroll
      for (int vl = 0; vl < 64; ++vl) {
        u64 b = __ballot((row >> vl) & 1);
        if (lane == vl) keep = b;
      }
      // lane vl owns var g*256 + vl*4 + j
      size_t vi = ((size_t)(g * 256 + lane * 4 + j)) * 1024 + (size_t)cbi * 2 +
                  (w >= 4 ? 1 : 0);
      vbs[vi] = keep;
    }
    __syncthreads();
  }

  // epilogue: relu + dmat = c @ fb1^T (all warps run 8 uniform iterations)
  for (int i = 0; i < 8; ++i) {
    int cl = w * 8 + i;
    float cv = fmaxf((float)acc[i] + cbias[lane], 0.f);
    crow[w][lane] = cv;
    __syncthreads();
    double da = 0.0;
#pragma unroll
    for (int k = 0; k < 64; ++k)
      da = fma((double)crow[w][k], (double)fbt[k * 64 + lane], da);
    dmat[(size_t)(c0 + cl) * 64 + lane] = (float)da;
    __syncthreads();
  }
}

// pass 2 (fast): per-variable gather. One wave per variable, no atomics.
__global__ __launch_bounds__(256) void k_gather(const u64* __restrict__ vbs,
                                                const float* __restrict__ dmat,
                                                float* __restrict__ nv) {
  int w = __builtin_amdgcn_readfirstlane(threadIdx.x >> 6);
  int lane = threadIdx.x & 63;
  int v = blockIdx.x * 4 + w;
  const u64* p = vbs + (size_t)v * 1024;   // 512 x {m, s}
  double acc = 0.0;
  for (int cc4 = 0; cc4 < 512; cc4 += 4) {
    u64 mm[4], ss[4];
#pragma unroll
    for (int q = 0; q < 4; ++q) {
      mm[q] = p[(cc4 + q) * 2];
      ss[q] = p[(cc4 + q) * 2 + 1];
    }
#pragma unroll
    for (int q = 0; q < 4; ++q) {
      u64 m = mm[q];
      u64 s = ss[q];
      size_t cbase = (size_t)(cc4 + q) << 12;   // (cc*64)*64 floats
      while (m) {
        int l = __builtin_ctzll(m);
        m &= m - 1;
        float dv = dmat[cbase + ((size_t)l << 6) + lane];
        acc += ((s >> l) & 1) ? -(double)dv : (double)dv;
      }
    }
  }
  nv[(size_t)v * 64 + lane] = (float)acc;
}

// ======================= FALLBACK PATH (ws too small) =======================
__global__ __launch_bounds__(256) void k_pass1_basic(
    const float* __restrict__ pos, const float* __restrict__ neg,
    const float* __restrict__ bmat, const float* __restrict__ fb1,
    const float* __restrict__ cbias, float* __restrict__ dmat) {
  __shared__ float fbt[64 * 64];
  __shared__ float crow[4][64];
  int t = threadIdx.x;
#pragma unroll
  for (int i = 0; i < 16; ++i) {
    int idx = i * 256 + t;
    fbt[(idx & 63) * 64 + (idx >> 6)] = fb1[idx];
  }
  __syncthreads();
  int w = t >> 6, lane = t & 63;
  int c = blockIdx.x * 4 + w;
  const float4* prow = (const float4*)(pos + (size_t)c * NVAR);
  const float4* nrow = (const float4*)(neg + (size_t)c * NVAR);
  double acc = 0.0;
  for (int g = 0; g < 32; ++g) {
    float4 p = prow[g * 64 + lane];
    float4 q = nrow[g * 64 + lane];
    float sc[4];
    sc[0] = p.x - q.x; sc[1] = p.y - q.y; sc[2] = p.z - q.z; sc[3] = p.w - q.w;
#pragma unroll
    for (int j = 0; j < 4; ++j) {
      float s = sc[j];
      u64 m = __ballot(s != 0.f);
      u64 sg = __ballot(s < 0.f);
      while (m) {
        int l = __builtin_ctzll(m);
        m &= m - 1;
        float dv = bmat[(size_t)((g << 8) + (l << 2) + j) * 64 + lane];
        acc += ((sg >> l) & 1) ? -(double)dv : (double)dv;
      }
    }
  }
  float cv = fmaxf((float)acc + cbias[lane], 0.f);
  crow[w][lane] = cv;
  __syncthreads();
  double da = 0.0;
#pragma unroll
  for (int k = 0; k < 64; ++k)
    da = fma((double)crow[w][k], (double)fbt[k * 64 + lane], da);
  dmat[(size_t)c * 64 + lane] = (float)da;
}

__global__ __launch_bounds__(256) void k_pass2_dense(
    const float* __restrict__ pos, const float* __restrict__ neg,
    const float* __restrict__ dmat, float* __restrict__ nv) {
  __shared__ float acc[64 * 64];
  int t = threadIdx.x;
#pragma unroll
  for (int i = 0; i < 16; ++i) acc[i * 256 + t] = 0.f;
  __syncthreads();
  int w = t >> 6, lane = t & 63;
  int s = blockIdx.x / CSEG, seg = blockIdx.x % CSEG;
  int c0 = seg * (NCLS / CSEG);
  for (int c = c0 + w; c < c0 + NCLS / CSEG; c += 4) {
    float p = pos[(size_t)c * NVAR + (s << 6) + lane];
    float q = neg[(size_t)c * NVAR + (s << 6) + lane];
    float sv = p - q;
    u64 m = __ballot(sv != 0.f);
    if (!m) continue;
    float dv = dmat[(size_t)c * 64 + lane];
    while (m) {
      int l = __builtin_ctzll(m);
      m &= m - 1;
      float sl = lane_bc(sv, l);
      atomicAdd(&acc[(l << 6) + lane], sl * dv);
    }
  }
  __syncthreads();
  size_t obase = (size_t)s * 4096;
#pragma unroll
  for (int i = 0; i < 16; ++i) {
    int idx = i * 256 + t;
    atomicAdd(&nv[obase + idx], acc[idx]);
  }
}

// ------- tail 1: ve2 = tanh(cat(ground, relu(nv+vb)) @ Wg^T + bg) -------
__global__ __launch_bounds__(256) void k_tail1(
    const float* __restrict__ nv, const float* __restrict__ vb,
    const float* __restrict__ ground, const float* __restrict__ Wg,
    const float* __restrict__ bg, float* __restrict__ ve2out) {
  __shared__ float wt[72 * 64];   // wt[k][d] = Wg[d][k]
  __shared__ float inrow[4][72];
  int t = threadIdx.x;
#pragma unroll
  for (int i = 0; i < 18; ++i) {
    int idx = i * 256 + t;                       // d*72+k
    wt[(idx % 72) * 64 + (idx / 72)] = Wg[idx];
  }
  __syncthreads();
  int w = t >> 6, lane = t & 63;
  for (int rr = 0; rr < 32; rr += 4) {
    int row = blockIdx.x * 32 + rr + w;
    float ve = fmaxf(nv[row * 64 + lane] + vb[lane], 0.f);
    inrow[w][8 + lane] = ve;
    if (lane < 8) inrow[w][lane] = ground[row * 8 + lane];
    __syncthreads();
    double a = 0.0;
#pragma unroll
    for (int k = 0; k < 72; ++k)
      a = fma((double)inrow[w][k], (double)wt[k * 64 + lane], a);
    ve2out[row * 64 + lane] = tanhf((float)a + bg[lane]);
    __syncthreads();
  }
}

// ------- tail GRU: M=0 -> z, M=1 -> rp=r*prev, M=2 -> h & final output -------
template <int M>
__global__ __launch_bounds__(256) void k_tailg(
    const float* __restrict__ ve2, const float* __restrict__ in2,
    const float* __restrict__ W, const float* __restrict__ U,
    const float* __restrict__ bias, const float* __restrict__ prev,
    const float* __restrict__ zbuf, float* __restrict__ outbuf) {
  __shared__ float wt[64 * 64], ut[64 * 64];
  __shared__ float xr[4][64], yr[4][64];
  int t = threadIdx.x;
#pragma unroll
  for (int i = 0; i < 16; ++i) {
    int idx = i * 256 + t;
    wt[(idx & 63) * 64 + (idx >> 6)] = W[idx];
    ut[(idx & 63) * 64 + (idx >> 6)] = U[idx];
  }
  __syncthreads();
  int w = t >> 6, lane = t & 63;
  for (int rr = 0; rr < 32; rr += 4) {
    int row = blockIdx.x * 32 + rr + w;
    xr[w][lane] = ve2[row * 64 + lane];
    yr[w][lane] = in2[row * 64 + lane];
    __syncthreads();
    float a = bias[lane];
#pragma unroll
    for (int k = 0; k < 64; ++k) a = fmaf(xr[w][k], wt[k * 64 + lane], a);
#pragma unroll
    for (int k = 0; k < 64; ++k) a = fmaf(yr[w][k], ut[k * 64 + lane], a);
    float res;
    if (M == 0) {
      res = 1.f / (1.f + expf(-a));
    } else if (M == 1) {
      float r = 1.f / (1.f + expf(-a));
      res = r * prev[row * 64 + lane];
    } else {
      float h = tanhf(a);
      float z = zbuf[row * 64 + lane];
      float p = prev[row * 64 + lane];
      res = (1.f - z) * p + z * h;
    }
    outbuf[row * 64 + lane] = res;
    __syncthreads();
  }
}

extern "C" void kernel_launch(void* const* d_in, const int* in_sizes, int n_in,
                              void* d_out, int out_size, void* d_ws, size_t ws_size,
                              hipStream_t stream) {
  const float* variables = (const float*)d_in[0];
  const float* ground    = (const float*)d_in[1];
  const float* cpos      = (const float*)d_in[2];
  const float* cneg      = (const float*)d_in[3];
  const float* fb        = (const float*)d_in[6];
  const float* vb        = (const float*)d_in[7];
  const float* cb        = (const float*)d_in[8];
  const float* Wg        = (const float*)d_in[9];
  const float* bg        = (const float*)d_in[10];
  const float* Wz        = (const float*)d_in[11];
  const float* Uz        = (const float*)d_in[12];
  const float* bz        = (const float*)d_in[13];
  const float* Wr        = (const float*)d_in[14];
  const float* Ur        = (const float*)d_in[15];
  const float* br        = (const float*)d_in[16];
  const float* Wh        = (const float*)d_in[17];
  const float* Uh        = (const float*)d_in[18];
  const float* bh        = (const float*)d_in[19];
  float* out = (float*)d_out;
  char* ws = (char*)d_ws;
  const size_t MB = (size_t)1 << 20;

  float* vfwd  = (float*)(ws + 0);        // 2 MB (later reused as ve2)
  float* dmat  = (float*)(ws + 2 * MB);   // 8 MB
  float* nv    = (float*)(ws + 10 * MB);  // 2 MB
  float* zbuf  = (float*)(ws + 12 * MB);  // 2 MB
  float* rpbuf = (float*)(ws + 14 * MB);  // 2 MB
  u64* vbs     = (u64*)(ws + 16 * MB);    // 64 MB: [var][512][2] {mask, sign}
  bool fast = ws_size >= 80 * MB;

  k_varsfwd<<<512, 256, 0, stream>>>(variables, fb, vfwd);
  if (fast) {
    k_pass1t<<<512, 512, 0, stream>>>(cpos, cneg, vfwd, fb + 4096, cb, dmat, vbs);
    k_gather<<<2048, 256, 0, stream>>>(vbs, dmat, nv);
  } else {
    k_pass1_basic<<<8192, 256, 0, stream>>>(cpos, cneg, vfwd, fb + 4096, cb, dmat);
    hipMemsetAsync(nv, 0, (size_t)NVAR * 64 * sizeof(float), stream);
    k_pass2_dense<<<128 * CSEG, 256, 0, stream>>>(cpos, cneg, dmat, nv);
  }
  k_tail1<<<256, 256, 0, stream>>>(nv, vb, ground, Wg, bg, vfwd);
  k_tailg<0><<<256, 256, 0, stream>>>(vfwd, variables, Wz, Uz, bz, variables,
                                      nullptr, zbuf);
  k_tailg<1><<<256, 256, 0, stream>>>(vfwd, variables, Wr, Ur, br, variables,
                                      nullptr, rpbuf);
  k_tailg<2><<<256, 256, 0, stream>>>(vfwd, rpbuf, Wh, Uh, bh, variables, zbuf,
                                      out);
}

// Round 3
// 1537.642 us; speedup vs baseline: 2.9142x; 1.2253x over previous
//
#include <hip/hip_runtime.h>
#include <stdint.h>

typedef unsigned long long u64;

#define NVAR 8192
#define NCLS 32768
#define CSEG 16

__device__ __forceinline__ float lane_bc(float v, int l) { return __shfl(v, l); }

// ---------------- kernel 1: vars_fwd = v @ fb0^T  [NVAR,64] ----------------
__global__ __launch_bounds__(256) void k_varsfwd(const float* __restrict__ v,
                                                 const float* __restrict__ fb0,
                                                 float* __restrict__ out) {
  __shared__ float fbt[64 * 64];   // fbt[k][d] = fb0[d][k]
  __shared__ float vrow[4][64];
  int t = threadIdx.x;
#pragma unroll
  for (int i = 0; i < 16; ++i) {
    int idx = i * 256 + t;                       // idx = d*64+k
    fbt[(idx & 63) * 64 + (idx >> 6)] = fb0[idx];
  }
  __syncthreads();
  int w = t >> 6, lane = t & 63;
  for (int rr = 0; rr < 16; rr += 4) {
    int row = blockIdx.x * 16 + rr + w;
    vrow[w][lane] = v[row * 64 + lane];
    __syncthreads();
    double a = 0.0;
#pragma unroll
    for (int k = 0; k < 64; ++k)
      a = fma((double)vrow[w][k], (double)fbt[k * 64 + lane], a);
    out[row * 64 + lane] = (float)a;
    __syncthreads();
  }
}

// ======================= FAST PATH =======================
// pass 1: block = 32 clauses (grid 1024 -> 4 blocks/CU, 32 waves/CU).
//   c = relu(cm @ vars_fwd + cb); dmat = c @ fb1^T
//   AND emit transposed bitmasks: vbs[var][cchunk][2] = {presence, sign},
//   each block writing its 32-bit half of the u64 word via u32 stores.
__global__ __launch_bounds__(512, 8) void k_pass1s(
    const float* __restrict__ pos, const float* __restrict__ neg,
    const float* __restrict__ vfwd, const float* __restrict__ fb1,
    const float* __restrict__ cbias, float* __restrict__ dmat,
    unsigned* __restrict__ vbs32) {
  __shared__ float fbt[64 * 64];   // fbt[k][d] = fb1[d][k]
  __shared__ u64 lm[32][4];        // [clause_local][j] presence over 64 vars
  __shared__ u64 lsg[32][4];       // sign bits
  __shared__ float crow[8][64];
  int t = threadIdx.x;
#pragma unroll
  for (int i = 0; i < 8; ++i) {
    int idx = i * 512 + t;
    fbt[(idx & 63) * 64 + (idx >> 6)] = fb1[idx];
  }
  int w = __builtin_amdgcn_readfirstlane(t >> 6);   // warp id 0..7 (SGPR)
  int lane = t & 63;
  int bx = blockIdx.x;             // 0..1023
  int c0 = bx * 32;                // first clause of block
  int cb = bx >> 1;                // clause chunk (64 clauses)
  int h = bx & 1;                  // which 32-bit half of the u64 word
  double acc[4];
#pragma unroll
  for (int i = 0; i < 4; ++i) acc[i] = 0.0;
  __syncthreads();

  for (int g = 0; g < 32; ++g) {   // 32 groups of 256 variables
#pragma unroll
    for (int i = 0; i < 4; ++i) {
      int cl = w * 4 + i;          // local clause 0..31
      size_t rb = (size_t)(c0 + cl) * 2048 + (size_t)g * 64 + lane; // float4
      float4 p = ((const float4*)pos)[rb];
      float4 q = ((const float4*)neg)[rb];
      float sc[4];
      sc[0] = p.x - q.x; sc[1] = p.y - q.y; sc[2] = p.z - q.z; sc[3] = p.w - q.w;
#pragma unroll
      for (int j = 0; j < 4; ++j) {
        float s = sc[j];
        u64 m = __ballot(s != 0.f);
        u64 sg = __ballot(s < 0.f);
        if (lane == j) { lm[cl][j] = m; lsg[cl][j] = sg; }
        while (m) {                // ~2.6 set bits per word
          int l = __builtin_ctzll(m);
          m &= m - 1;
          float dv = vfwd[(size_t)((g << 8) + (l << 2) + j) * 64 + lane];
          acc[i] += ((sg >> l) & 1) ? -(double)dv : (double)dv;  // exact
        }
      }
    }
    __syncthreads();
    // bit-transpose: 8 warps, tile (k = w>>2: 0=mask,1=sign; j = w&3).
    // rows = 32 clauses (lanes 0-31), columns = 64 vars.
    {
      int k = w >> 2, j = w & 3;
      u64 row = 0;
      if (lane < 32) row = k ? lsg[lane][j] : lm[lane][j];
      unsigned keep = 0;
#pragma unroll
      for (int vl = 0; vl < 64; ++vl) {
        u64 b = __ballot((row >> vl) & 1);   // bits 0..31 = clauses
        if (lane == vl) keep = (unsigned)b;
      }
      int v = g * 256 + lane * 4 + j;
      vbs32[((size_t)(v * 512 + cb) * 2 + k) * 2 + h] = keep;
    }
    __syncthreads();
  }

  // epilogue: relu + dmat = c @ fb1^T (each warp owns its 4 clauses)
  for (int i = 0; i < 4; ++i) {
    int cl = w * 4 + i;
    float cv = fmaxf((float)acc[i] + cbias[lane], 0.f);
    crow[w][lane] = cv;
    __syncthreads();
    double da = 0.0;
#pragma unroll
    for (int k = 0; k < 64; ++k)
      da = fma((double)crow[w][k], (double)fbt[k * 64 + lane], da);
    dmat[(size_t)(c0 + cl) * 64 + lane] = (float)da;
    __syncthreads();
  }
}

// pass 2 (fast): per-variable gather. One wave per variable, no atomics.
__global__ __launch_bounds__(256, 8) void k_gather(const u64* __restrict__ vbs,
                                                   const float* __restrict__ dmat,
                                                   float* __restrict__ nv) {
  int w = __builtin_amdgcn_readfirstlane(threadIdx.x >> 6);
  int lane = threadIdx.x & 63;
  int v = blockIdx.x * 4 + w;
  const u64* p = vbs + (size_t)v * 1024;   // 512 x {m, s}
  double acc = 0.0;
  for (int cc4 = 0; cc4 < 512; cc4 += 4) {
    u64 mm[4], ss[4];
#pragma unroll
    for (int q = 0; q < 4; ++q) {
      mm[q] = p[(cc4 + q) * 2];
      ss[q] = p[(cc4 + q) * 2 + 1];
    }
#pragma unroll
    for (int q = 0; q < 4; ++q) {
      u64 m = mm[q];
      u64 s = ss[q];
      size_t cbase = (size_t)(cc4 + q) << 12;   // (cc*64)*64 floats
      while (m) {
        int l = __builtin_ctzll(m);
        m &= m - 1;
        float dv = dmat[cbase + ((size_t)l << 6) + lane];
        acc += ((s >> l) & 1) ? -(double)dv : (double)dv;
      }
    }
  }
  nv[(size_t)v * 64 + lane] = (float)acc;
}

// ======================= FALLBACK PATH (ws too small) =======================
__global__ __launch_bounds__(256) void k_pass1_basic(
    const float* __restrict__ pos, const float* __restrict__ neg,
    const float* __restrict__ bmat, const float* __restrict__ fb1,
    const float* __restrict__ cbias, float* __restrict__ dmat) {
  __shared__ float fbt[64 * 64];
  __shared__ float crow[4][64];
  int t = threadIdx.x;
#pragma unroll
  for (int i = 0; i < 16; ++i) {
    int idx = i * 256 + t;
    fbt[(idx & 63) * 64 + (idx >> 6)] = fb1[idx];
  }
  __syncthreads();
  int w = t >> 6, lane = t & 63;
  int c = blockIdx.x * 4 + w;
  const float4* prow = (const float4*)(pos + (size_t)c * NVAR);
  const float4* nrow = (const float4*)(neg + (size_t)c * NVAR);
  double acc = 0.0;
  for (int g = 0; g < 32; ++g) {
    float4 p = prow[g * 64 + lane];
    float4 q = nrow[g * 64 + lane];
    float sc[4];
    sc[0] = p.x - q.x; sc[1] = p.y - q.y; sc[2] = p.z - q.z; sc[3] = p.w - q.w;
#pragma unroll
    for (int j = 0; j < 4; ++j) {
      float s = sc[j];
      u64 m = __ballot(s != 0.f);
      u64 sg = __ballot(s < 0.f);
      while (m) {
        int l = __builtin_ctzll(m);
        m &= m - 1;
        float dv = bmat[(size_t)((g << 8) + (l << 2) + j) * 64 + lane];
        acc += ((sg >> l) & 1) ? -(double)dv : (double)dv;
      }
    }
  }
  float cv = fmaxf((float)acc + cbias[lane], 0.f);
  crow[w][lane] = cv;
  __syncthreads();
  double da = 0.0;
#pragma unroll
  for (int k = 0; k < 64; ++k)
    da = fma((double)crow[w][k], (double)fbt[k * 64 + lane], da);
  dmat[(size_t)c * 64 + lane] = (float)da;
}

__global__ __launch_bounds__(256) void k_pass2_dense(
    const float* __restrict__ pos, const float* __restrict__ neg,
    const float* __restrict__ dmat, float* __restrict__ nv) {
  __shared__ float acc[64 * 64];
  int t = threadIdx.x;
#pragma unroll
  for (int i = 0; i < 16; ++i) acc[i * 256 + t] = 0.f;
  __syncthreads();
  int w = t >> 6, lane = t & 63;
  int s = blockIdx.x / CSEG, seg = blockIdx.x % CSEG;
  int c0 = seg * (NCLS / CSEG);
  for (int c = c0 + w; c < c0 + NCLS / CSEG; c += 4) {
    float p = pos[(size_t)c * NVAR + (s << 6) + lane];
    float q = neg[(size_t)c * NVAR + (s << 6) + lane];
    float sv = p - q;
    u64 m = __ballot(sv != 0.f);
    if (!m) continue;
    float dv = dmat[(size_t)c * 64 + lane];
    while (m) {
      int l = __builtin_ctzll(m);
      m &= m - 1;
      float sl = lane_bc(sv, l);
      atomicAdd(&acc[(l << 6) + lane], sl * dv);
    }
  }
  __syncthreads();
  size_t obase = (size_t)s * 4096;
#pragma unroll
  for (int i = 0; i < 16; ++i) {
    int idx = i * 256 + t;
    atomicAdd(&nv[obase + idx], acc[idx]);
  }
}

// ------- tail 1: ve2 = tanh(cat(ground, relu(nv+vb)) @ Wg^T + bg) -------
__global__ __launch_bounds__(256) void k_tail1(
    const float* __restrict__ nv, const float* __restrict__ vb,
    const float* __restrict__ ground, const float* __restrict__ Wg,
    const float* __restrict__ bg, float* __restrict__ ve2out) {
  __shared__ float wt[72 * 64];   // wt[k][d] = Wg[d][k]
  __shared__ float inrow[4][72];
  int t = threadIdx.x;
#pragma unroll
  for (int i = 0; i < 18; ++i) {
    int idx = i * 256 + t;                       // d*72+k
    wt[(idx % 72) * 64 + (idx / 72)] = Wg[idx];
  }
  __syncthreads();
  int w = t >> 6, lane = t & 63;
  for (int rr = 0; rr < 32; rr += 4) {
    int row = blockIdx.x * 32 + rr + w;
    float ve = fmaxf(nv[row * 64 + lane] + vb[lane], 0.f);
    inrow[w][8 + lane] = ve;
    if (lane < 8) inrow[w][lane] = ground[row * 8 + lane];
    __syncthreads();
    double a = 0.0;
#pragma unroll
    for (int k = 0; k < 72; ++k)
      a = fma((double)inrow[w][k], (double)wt[k * 64 + lane], a);
    ve2out[row * 64 + lane] = tanhf((float)a + bg[lane]);
    __syncthreads();
  }
}

// ------- tail GRU: M=0 -> z, M=1 -> rp=r*prev, M=2 -> h & final output -------
template <int M>
__global__ __launch_bounds__(256) void k_tailg(
    const float* __restrict__ ve2, const float* __restrict__ in2,
    const float* __restrict__ W, const float* __restrict__ U,
    const float* __restrict__ bias, const float* __restrict__ prev,
    const float* __restrict__ zbuf, float* __restrict__ outbuf) {
  __shared__ float wt[64 * 64], ut[64 * 64];
  __shared__ float xr[4][64], yr[4][64];
  int t = threadIdx.x;
#pragma unroll
  for (int i = 0; i < 16; ++i) {
    int idx = i * 256 + t;
    wt[(idx & 63) * 64 + (idx >> 6)] = W[idx];
    ut[(idx & 63) * 64 + (idx >> 6)] = U[idx];
  }
  __syncthreads();
  int w = t >> 6, lane = t & 63;
  for (int rr = 0; rr < 32; rr += 4) {
    int row = blockIdx.x * 32 + rr + w;
    xr[w][lane] = ve2[row * 64 + lane];
    yr[w][lane] = in2[row * 64 + lane];
    __syncthreads();
    float a = bias[lane];
#pragma unroll
    for (int k = 0; k < 64; ++k) a = fmaf(xr[w][k], wt[k * 64 + lane], a);
#pragma unroll
    for (int k = 0; k < 64; ++k) a = fmaf(yr[w][k], ut[k * 64 + lane], a);
    float res;
    if (M == 0) {
      res = 1.f / (1.f + expf(-a));
    } else if (M == 1) {
      float r = 1.f / (1.f + expf(-a));
      res = r * prev[row * 64 + lane];
    } else {
      float h = tanhf(a);
      float z = zbuf[row * 64 + lane];
      float p = prev[row * 64 + lane];
      res = (1.f - z) * p + z * h;
    }
    outbuf[row * 64 + lane] = res;
    __syncthreads();
  }
}

extern "C" void kernel_launch(void* const* d_in, const int* in_sizes, int n_in,
                              void* d_out, int out_size, void* d_ws, size_t ws_size,
                              hipStream_t stream) {
  const float* variables = (const float*)d_in[0];
  const float* ground    = (const float*)d_in[1];
  const float* cpos      = (const float*)d_in[2];
  const float* cneg      = (const float*)d_in[3];
  const float* fb        = (const float*)d_in[6];
  const float* vb        = (const float*)d_in[7];
  const float* cb        = (const float*)d_in[8];
  const float* Wg        = (const float*)d_in[9];
  const float* bg        = (const float*)d_in[10];
  const float* Wz        = (const float*)d_in[11];
  const float* Uz        = (const float*)d_in[12];
  const float* bz        = (const float*)d_in[13];
  const float* Wr        = (const float*)d_in[14];
  const float* Ur        = (const float*)d_in[15];
  const float* br        = (const float*)d_in[16];
  const float* Wh        = (const float*)d_in[17];
  const float* Uh        = (const float*)d_in[18];
  const float* bh        = (const float*)d_in[19];
  float* out = (float*)d_out;
  char* ws = (char*)d_ws;
  const size_t MB = (size_t)1 << 20;

  float* vfwd  = (float*)(ws + 0);        // 2 MB (later reused as ve2)
  float* dmat  = (float*)(ws + 2 * MB);   // 8 MB
  float* nv    = (float*)(ws + 10 * MB);  // 2 MB
  float* zbuf  = (float*)(ws + 12 * MB);  // 2 MB
  float* rpbuf = (float*)(ws + 14 * MB);  // 2 MB
  u64* vbs     = (u64*)(ws + 16 * MB);    // 64 MB: [var][512][2] {mask, sign}
  bool fast = ws_size >= 80 * MB;

  k_varsfwd<<<512, 256, 0, stream>>>(variables, fb, vfwd);
  if (fast) {
    k_pass1s<<<1024, 512, 0, stream>>>(cpos, cneg, vfwd, fb + 4096, cb, dmat,
                                       (unsigned*)vbs);
    k_gather<<<2048, 256, 0, stream>>>(vbs, dmat, nv);
  } else {
    k_pass1_basic<<<8192, 256, 0, stream>>>(cpos, cneg, vfwd, fb + 4096, cb, dmat);
    hipMemsetAsync(nv, 0, (size_t)NVAR * 64 * sizeof(float), stream);
    k_pass2_dense<<<128 * CSEG, 256, 0, stream>>>(cpos, cneg, dmat, nv);
  }
  k_tail1<<<256, 256, 0, stream>>>(nv, vb, ground, Wg, bg, vfwd);
  k_tailg<0><<<256, 256, 0, stream>>>(vfwd, variables, Wz, Uz, bz, variables,
                                      nullptr, zbuf);
  k_tailg<1><<<256, 256, 0, stream>>>(vfwd, variables, Wr, Ur, br, variables,
                                      nullptr, rpbuf);
  k_tailg<2><<<256, 256, 0, stream>>>(vfwd, rpbuf, Wh, Uh, bh, variables, zbuf,
                                      out);
}